// Round 10
// baseline (212.091 us; speedup 1.0000x reference)
//
#include <hip/hip_runtime.h>
#include <hip/hip_bf16.h>

// LocalCorrelation, round 10: barrier-free K-loop.
// K1: z_t1 fp32 [B,C,H,W] -> bf16 [B,H,W,C] in d_ws (+4KB zero page).
// K2: B-fragments loaded straight from HWC global to registers (16-B
//     dwordx4 per lane per frag; OOB lanes read the zero page). No LDS,
//     no pack, no barriers in the K-loop -> waves fully desynchronized,
//     latency hidden by per-wave MLP + 12 waves/CU. A-operand packed to
//     registers once per block. LDS used only by the verified epilogue.

#define CHPL 16384
#define NT 169
#define KHALF 85
#define OSTRIDE 132
#define ZPG 4096                    // zero page bytes at ws start

typedef __attribute__((ext_vector_type(8))) short bf16x8;
typedef __attribute__((ext_vector_type(4))) float f32x4;
typedef unsigned int u32;
typedef unsigned short u16;

static __device__ __forceinline__ u32 pk2(float a, float b) {
    __hip_bfloat162 h = __float22bfloat162_rn(make_float2(a, b));
    union { __hip_bfloat162 h2; u32 u; } c; c.h2 = h; return c.u;
}

// ---------- K1: cast + transpose z_t1 -> bf16 HWC (R9-verified) ----------
__global__ __launch_bounds__(256)
void lc_tr(const float* __restrict__ zt1, void* __restrict__ ws) {
    __shared__ float ld[64][68];
    const int tid = threadIdx.x, bid = blockIdx.x;
    const int cb = bid & 3, wb = (bid >> 2) & 1;
    const int h = (bid >> 3) & 127, b = bid >> 10;
    if (bid == 0) ((uint4*)ws)[tid] = make_uint4(0u, 0u, 0u, 0u);  // 4KB zeros
    const int c0 = cb * 64, w0 = wb * 64;
#pragma unroll
    for (int k = 0; k < 4; ++k) {
        const int u = tid + k * 256, ch = u >> 4, seg = u & 15;
        const float4 v = *(const float4*)(zt1 + ((size_t)(b * 256 + c0 + ch)) * CHPL
                                          + h * 128 + w0 + seg * 4);
        *(float4*)&ld[ch][seg * 4] = v;
    }
    __syncthreads();
    const int px = tid >> 2, part = tid & 3;
    u32 r[8];
#pragma unroll
    for (int j = 0; j < 8; ++j)
        r[j] = pk2(ld[part * 16 + 2 * j][px], ld[part * 16 + 2 * j + 1][px]);
    u16* dst = (u16*)((char*)ws + ZPG)
               + ((size_t)(b * 16384 + h * 128 + w0 + px)) * 256 + c0 + part * 16;
    *(uint4*)dst = make_uint4(r[0], r[1], r[2], r[3]);
    *(uint4*)(dst + 8) = make_uint4(r[4], r[5], r[6], r[7]);
}

// ---------- K2: correlation, barrier-free K-loop ----------
__global__ __launch_bounds__(512)
void lc10(const float* __restrict__ zt, const void* __restrict__ ws,
          float* __restrict__ out) {
    __shared__ union { char raw[KHALF * OSTRIDE * 4]; float outb[KHALF * OSTRIDE]; } sm;
    const int tid = threadIdx.x, lane = tid & 63, wid = tid >> 6;
    const int bid = blockIdx.x;
    const int b = bid & 7, t = bid >> 3;              // one batch per XCD
    const int h0 = (t >> 3) * 8, w0 = (t & 7) * 16;
    const int py0 = (wid >> 2) * 4, px0 = (wid & 3) * 4;
    const int nlo = lane & 3, nhi = (lane >> 2) & 3, oo = lane >> 4;

    const char* wsb = (const char*)ws;                // zero page at offset 0

    // ---- B-frag byte offsets (from ws base; OOB -> zero page) ----
    u32 off[16];
#pragma unroll
    for (int qi = 0; qi < 16; ++qi) {
        const int qyL = py0 + (qi >> 2) * 4 + nhi;
        const int qxL = px0 + (qi & 3) * 4 + nlo;
        const int gy = h0 + qyL - 6, gx = w0 + qxL - 6;
        const bool val = (gy >= 0) && (gy < 128) && (gx >= 0) && (gx < 128);
        off[qi] = val ? (u32)(ZPG + ((size_t)(b * 16384 + gy * 128 + gx)) * 512
                              + oo * 16)
                      : (u32)(lane * 16);   // + kc*64 stays within 4KB zeros
    }

    // ---- A-operand: global->reg once, pack to bf16 (R7-verified) ----
    bf16x8 abf[8];
    {
        const float* ap = zt + (((size_t)(b * 256 + oo * 8)) * CHPL
                                + (h0 + py0 + nhi) * 128 + (w0 + px0 + nlo));
#pragma unroll
        for (int pr = 0; pr < 8; ++pr) {
            float a8[8];
#pragma unroll
            for (int e = 0; e < 8; ++e) a8[e] = ap[(size_t)(pr * 32 + e) * CHPL];
            union { u32 u[4]; bf16x8 v; } au;
            au.u[0] = pk2(a8[0], a8[1]); au.u[1] = pk2(a8[2], a8[3]);
            au.u[2] = pk2(a8[4], a8[5]); au.u[3] = pk2(a8[6], a8[7]);
            abf[pr] = au.v;
        }
    }

    f32x4 acc[16];
#pragma unroll
    for (int qi = 0; qi < 16; ++qi) acc[qi] = (f32x4){0.f, 0.f, 0.f, 0.f};

    // ---- K-loop: 128 independent 16-B loads + 128 MFMA, no barriers ----
#pragma unroll
    for (int kc = 0; kc < 8; ++kc) {
#pragma unroll
        for (int qi = 0; qi < 16; ++qi) {
            const bf16x8 bfr = *(const bf16x8*)(wsb + off[qi] + kc * 64);
            acc[qi] = __builtin_amdgcn_mfma_f32_16x16x32_bf16(abf[kc], bfr, acc[qi], 0, 0, 0);
        }
    }

    // ---- epilogue (R2-R9-verified): stage k-planes through LDS ----
    // C/D: n = lane&15 (q-px), m = oo*4 + r -> py = py0+oo, px = px0+r
    const int psb = (py0 + oo) * 16 + px0;
#pragma unroll 1
    for (int pass = 0; pass < 2; ++pass) {
        const int kb = pass * KHALF;
        const int nk = pass ? (NT - KHALF) : KHALF;   // 85 / 84
        __syncthreads();
#pragma unroll
        for (int qi = 0; qi < 16; ++qi) {
            const int di = 4 * (qi >> 2) + nhi - oo;
            const bool diok = (unsigned)di <= 12u;
            const int dib = di * 13;
#pragma unroll
            for (int r = 0; r < 4; ++r) {
                const int dj = 4 * (qi & 3) + nlo - r;
                const int k  = dib + dj;
                if (diok && (unsigned)dj <= 12u && k >= kb && k < kb + nk)
                    sm.outb[(k - kb) * OSTRIDE + psb + r] = acc[qi][r] * 0.0625f;
            }
        }
        __syncthreads();
        const int total4 = nk * 32;
        for (int i = tid; i < total4; i += 512) {
            const int row = i >> 5, j = i & 31;
            const float4 val = *(const float4*)&sm.outb[row * OSTRIDE + j * 4];
            float* dst = out + (((size_t)(b * NT + kb + row) * 128 + h0 + (j >> 2)) * 128
                                + w0 + (j & 3) * 4);
            *(float4*)dst = val;
        }
    }
}

extern "C" void kernel_launch(void* const* d_in, const int* in_sizes, int n_in,
                              void* d_out, int out_size, void* d_ws, size_t ws_size,
                              hipStream_t stream) {
    const float* zt  = (const float*)d_in[0];
    const float* zt1 = (const float*)d_in[1];
    float* out = (float*)d_out;
    lc_tr<<<dim3(8192), dim3(256), 0, stream>>>(zt1, d_ws);
    lc10<<<dim3(1024), dim3(512), 0, stream>>>(zt, d_ws, out);
}